// Round 1
// baseline (7455.434 us; speedup 1.0000x reference)
//
#include <hip/hip_runtime.h>
#include <stdint.h>

#define T_LEN 1024
#define BATCH 32
#define DIN   512
#define HID   512
#define G3    1536          // 3*HID
#define ROWS  (T_LEN*BATCH) // 32768

typedef short bf16x8 __attribute__((ext_vector_type(8)));
typedef float f32x4  __attribute__((ext_vector_type(4)));

__device__ __forceinline__ unsigned short f2bf(float f) {
  union { float f; uint32_t u; } v; v.f = f;
  uint32_t u = v.u;
  return (unsigned short)((u + 0x7fffu + ((u >> 16) & 1u)) >> 16);  // RNE
}
__device__ __forceinline__ float bf2f(unsigned short h) {
  union { uint32_t u; float f; } v; v.u = ((uint32_t)h) << 16; return v.f;
}
__device__ __forceinline__ float sigm(float x)   { return 1.f / (1.f + __expf(-x)); }
__device__ __forceinline__ float tanh_f(float x) { return 2.f / (1.f + __expf(-2.f * x)) - 1.f; }

// ---------------- zero init (stats + flags) ----------------
__global__ void zero_init(float* stats, int* cnt) {
  int i = blockIdx.x * 256 + threadIdx.x;
  if (i < 2 * G3) stats[i] = 0.f;
  if (i < 2 * T_LEN) cnt[i] = 0;
}

// ---------------- f32 -> bf16 convert ----------------
__global__ void convert_bf16(const float* __restrict__ src, unsigned short* __restrict__ dst, int n4) {
  int i = blockIdx.x * 256 + threadIdx.x;
  if (i < n4) {
    float4 v = ((const float4*)src)[i];
    ushort4 o;
    o.x = f2bf(v.x); o.y = f2bf(v.y); o.z = f2bf(v.z); o.w = f2bf(v.w);
    ((ushort4*)dst)[i] = o;
  }
}

// ---------------- P = x @ Wx^T  (bf16 in, bf16 out, fp32 acc) ----------------
// grid (512, 24), 256 threads = 4 waves; wave computes 32x32 via 2x2 MFMA 16x16x32 tiles.
__global__ __launch_bounds__(256) void gemm_proj(const unsigned short* __restrict__ xb,
                                                 const unsigned short* __restrict__ wxb,
                                                 unsigned short* __restrict__ P) {
  int w = threadIdx.x >> 6;
  int l = threadIdx.x & 63;
  int mi = w >> 1, ni = w & 1;
  int row_base = blockIdx.x * 64 + mi * 32;
  int col_base = blockIdx.y * 64 + ni * 32;
  int lr = l & 15, lk8 = (l >> 4) * 8;
  f32x4 acc00 = {0,0,0,0}, acc01 = {0,0,0,0}, acc10 = {0,0,0,0}, acc11 = {0,0,0,0};
  #pragma unroll 4
  for (int kk = 0; kk < 16; ++kk) {
    int k0 = kk * 32 + lk8;
    bf16x8 a0 = *(const bf16x8*)(xb  + (size_t)(row_base + lr) * DIN + k0);
    bf16x8 a1 = *(const bf16x8*)(xb  + (size_t)(row_base + 16 + lr) * DIN + k0);
    bf16x8 b0 = *(const bf16x8*)(wxb + (size_t)(col_base + lr) * DIN + k0);
    bf16x8 b1 = *(const bf16x8*)(wxb + (size_t)(col_base + 16 + lr) * DIN + k0);
    acc00 = __builtin_amdgcn_mfma_f32_16x16x32_bf16(a0, b0, acc00, 0, 0, 0);
    acc01 = __builtin_amdgcn_mfma_f32_16x16x32_bf16(a0, b1, acc01, 0, 0, 0);
    acc10 = __builtin_amdgcn_mfma_f32_16x16x32_bf16(a1, b0, acc10, 0, 0, 0);
    acc11 = __builtin_amdgcn_mfma_f32_16x16x32_bf16(a1, b1, acc11, 0, 0, 0);
  }
  // D layout: row = (l>>4)*4 + r, col = l&15   [measured m89]
  int rrow = (l >> 4) * 4;
  #pragma unroll
  for (int r = 0; r < 4; ++r) {
    P[(size_t)(row_base +      rrow + r) * G3 + col_base +      lr] = f2bf(acc00[r]);
    P[(size_t)(row_base +      rrow + r) * G3 + col_base + 16 + lr] = f2bf(acc01[r]);
    P[(size_t)(row_base + 16 + rrow + r) * G3 + col_base +      lr] = f2bf(acc10[r]);
    P[(size_t)(row_base + 16 + rrow + r) * G3 + col_base + 16 + lr] = f2bf(acc11[r]);
  }
}

// ---------------- per-channel sums over rows ----------------
__global__ void bn_stats(const unsigned short* __restrict__ P, float* __restrict__ stats) {
  int col = blockIdx.x * 256 + threadIdx.x;   // grid.x = 6  -> 1536 cols
  int r0  = blockIdx.y * 512;                 // grid.y = 64 -> 32768 rows
  float s = 0.f, q = 0.f;
  for (int r = 0; r < 512; ++r) {
    float v = bf2f(P[(size_t)(r0 + r) * G3 + col]);
    s += v; q += v * v;
  }
  atomicAdd(&stats[col], s);
  atomicAdd(&stats[G3 + col], q);
}

// ---------------- fold BN into scale/shift ----------------
__global__ void bn_final(const float* __restrict__ stats, const float* __restrict__ gamma,
                         const float* __restrict__ beta, float* __restrict__ params) {
  int c = blockIdx.x * 256 + threadIdx.x;
  if (c >= G3) return;
  float mean = stats[c] * (1.f / ROWS);
  float var  = stats[G3 + c] * (1.f / ROWS) - mean * mean;
  float sc = gamma[c] * rsqrtf(var + 1e-5f);
  params[c] = sc;
  params[G3 + c] = beta[c] - mean * sc;
}

// ---------------- the bidirectional GRU scan ----------------
// 64 blocks: blocks [0,32) forward, [32,64) backward. Block owns h-columns
// [s*16, s*16+16) => Wh rows {g*512 + j} for g in {r,z,n}, register-resident.
// 384 threads = 6 waves: wave w -> (gate = w>>1, mi = w&1) computes 16x16 tile
// of hp over full K=512. h broadcast through a 1024-deep bf16 history with
// per-step agent-scope release/acquire counters (no grid barrier).
__global__ __launch_bounds__(384) void scan_kernel(
    const unsigned short* __restrict__ P, const float* __restrict__ params,
    const unsigned short* __restrict__ whf, const unsigned short* __restrict__ whb,
    unsigned short* __restrict__ histf, unsigned short* __restrict__ histb,
    int* __restrict__ cnt) {
  int blk = blockIdx.x;
  int d = blk >> 5;
  int s = blk & 31;
  int j0 = s * 16;
  int tid = threadIdx.x;
  int w = tid >> 6, l = tid & 63;
  int gate = w >> 1, mi = w & 1;
  int lr = l & 15, lk8 = (l >> 4) * 8;

  const unsigned short* wh = d ? whb : whf;
  unsigned short* myhist = d ? histb : histf;
  int* mycnt = cnt + d * T_LEN;

  // B fragments (Wh slice) resident in VGPRs: B[k][n] = Wh[gate*512+j0+n][k]
  bf16x8 bfrag[16];
  {
    const unsigned short* wrow = wh + (size_t)(gate * HID + j0 + lr) * HID;
    #pragma unroll
    for (int kk = 0; kk < 16; ++kk)
      bfrag[kk] = *(const bf16x8*)(wrow + kk * 32 + lk8);
  }

  __shared__ __align__(16) char hlds[BATCH * HID * 2]; // 32 KB, XOR-swizzled bf16 h
  __shared__ float hp[3][BATCH][16];                   // 6 KB gate pre-activations

  // gate-phase items: item i -> (b = i>>4, jj = i&15), threads handle i=tid and i=tid+384
  int b1 = tid >> 4, jj1 = tid & 15, c1 = j0 + jj1;
  bool has2 = (tid < 128);
  int i2 = tid + 384;
  int b2 = i2 >> 4, jj2 = i2 & 15, c2 = j0 + jj2;
  // BN scale/shift for this thread's columns (loop-invariant)
  float scr1 = params[c1],           shr1 = params[G3 + c1];
  float scz1 = params[HID + c1],     shz1 = params[G3 + HID + c1];
  float scn1 = params[2 * HID + c1], shn1 = params[G3 + 2 * HID + c1];
  float scr2 = 0, shr2 = 0, scz2 = 0, shz2 = 0, scn2 = 0, shn2 = 0;
  if (has2) {
    scr2 = params[c2];           shr2 = params[G3 + c2];
    scz2 = params[HID + c2];     shz2 = params[G3 + HID + c2];
    scn2 = params[2 * HID + c2]; shn2 = params[G3 + 2 * HID + c2];
  }

  for (int t = 0; t < T_LEN; ++t) {
    int time = d ? (T_LEN - 1 - t) : t;
    // prefetch raw x-projection values (independent of h -> issue before wait)
    const unsigned short* prow1 = P + (size_t)(time * BATCH + b1) * G3 + c1;
    float xr1 = bf2f(prow1[0]), xz1 = bf2f(prow1[HID]), xn1 = bf2f(prow1[2 * HID]);
    float xr2 = 0, xz2 = 0, xn2 = 0;
    if (has2) {
      const unsigned short* prow2 = P + (size_t)(time * BATCH + b2) * G3 + c2;
      xr2 = bf2f(prow2[0]); xz2 = bf2f(prow2[HID]); xn2 = bf2f(prow2[2 * HID]);
    }

    if (t > 0) {
      if (tid == 0) {
        int guard = 0;
        while (__hip_atomic_load(mycnt + (t - 1), __ATOMIC_RELAXED, __HIP_MEMORY_SCOPE_AGENT) < 32) {
          __builtin_amdgcn_s_sleep(1);
          if (++guard > (1 << 14)) break;   // bailout: wrong answer beats a hang
        }
      }
      __syncthreads();
      // per-wave acquire -> invalidate L1/L2 before reading other XCDs' h writes
      (void)__hip_atomic_load(mycnt + (t - 1), __ATOMIC_ACQUIRE, __HIP_MEMORY_SCOPE_AGENT);
      const unsigned short* hprev = myhist + (size_t)(t - 1) * BATCH * HID;
      #pragma unroll
      for (int i = 0; i < 6; ++i) {
        int c = tid + i * 384;
        if (c < 2048) {
          bf16x8 v = *(const bf16x8*)((const char*)hprev + c * 16);
          int row = c >> 6;
          *(bf16x8*)(hlds + ((c * 16) ^ ((row & 7) << 4))) = v;
        }
      }
    } else {
      bf16x8 z = {0, 0, 0, 0, 0, 0, 0, 0};
      #pragma unroll
      for (int i = 0; i < 6; ++i) {
        int c = tid + i * 384;
        if (c < 2048) *(bf16x8*)(hlds + c * 16) = z;
      }
    }
    __syncthreads();

    // hp tile: A = h (M=32 rows, this wave rows mi*16..+16), B resident
    f32x4 acc = {0, 0, 0, 0};
    {
      int row = mi * 16 + lr;
      int rbase = row * 1024;
      int sw = (row & 7) << 4;
      #pragma unroll
      for (int kk = 0; kk < 16; ++kk) {
        bf16x8 a = *(const bf16x8*)(hlds + ((rbase + kk * 64 + lk8 * 2) ^ sw));
        acc = __builtin_amdgcn_mfma_f32_16x16x32_bf16(a, bfrag[kk], acc, 0, 0, 0);
      }
    }
    {
      int rrow = mi * 16 + (l >> 4) * 4;
      #pragma unroll
      for (int r = 0; r < 4; ++r) hp[gate][rrow + r][lr] = acc[r];
    }
    __syncthreads();

    // gates + h update
    unsigned short* hout = myhist + (size_t)t * BATCH * HID;
    {
      float rp = hp[0][b1][jj1], zp = hp[1][b1][jj1], np = hp[2][b1][jj1];
      float rv = sigm(fmaf(xr1, scr1, shr1) + rp);
      float zv = sigm(fmaf(xz1, scz1, shz1) + zp);
      float nv = tanh_f(fmaf(xn1, scn1, shn1) + rv * np);
      float hold = bf2f(*(const unsigned short*)(hlds + ((b1 * 1024 + c1 * 2) ^ ((b1 & 7) << 4))));
      hout[b1 * HID + c1] = f2bf((1.f - zv) * hold + zv * nv);
    }
    if (has2) {
      float rp = hp[0][b2][jj2], zp = hp[1][b2][jj2], np = hp[2][b2][jj2];
      float rv = sigm(fmaf(xr2, scr2, shr2) + rp);
      float zv = sigm(fmaf(xz2, scz2, shz2) + zp);
      float nv = tanh_f(fmaf(xn2, scn2, shn2) + rv * np);
      float hold = bf2f(*(const unsigned short*)(hlds + ((b2 * 1024 + c2 * 2) ^ ((b2 & 7) << 4))));
      hout[b2 * HID + c2] = f2bf((1.f - zv) * hold + zv * nv);
    }
    __syncthreads();                 // all hist writes of this block done
    if (tid == 0)
      __hip_atomic_fetch_add(mycnt + t, 1, __ATOMIC_RELEASE, __HIP_MEMORY_SCOPE_AGENT);
  }
}

// ---------------- out[t] = fwd[t] + bwd[T-1-t] ----------------
__global__ void final_add(const unsigned short* __restrict__ histf,
                          const unsigned short* __restrict__ histb,
                          float* __restrict__ out) {
  size_t i4 = (size_t)blockIdx.x * 256 + threadIdx.x;  // 4,194,304 threads
  size_t e = i4 * 4;
  int t = (int)(e / (BATCH * HID));
  size_t rem = e % (BATCH * HID);
  ushort4 vf = *(const ushort4*)(histf + e);
  ushort4 vb = *(const ushort4*)(histb + (size_t)(T_LEN - 1 - t) * BATCH * HID + rem);
  float4 o;
  o.x = bf2f(vf.x) + bf2f(vb.x);
  o.y = bf2f(vf.y) + bf2f(vb.y);
  o.z = bf2f(vf.z) + bf2f(vb.z);
  o.w = bf2f(vf.w) + bf2f(vb.w);
  *(float4*)(out + e) = o;
}

extern "C" void kernel_launch(void* const* d_in, const int* in_sizes, int n_in,
                              void* d_out, int out_size, void* d_ws, size_t ws_size,
                              hipStream_t stream) {
  const float* x     = (const float*)d_in[0];
  const float* Wx    = (const float*)d_in[1];
  const float* Whf   = (const float*)d_in[2];
  const float* Whb   = (const float*)d_in[3];
  const float* gamma = (const float*)d_in[4];
  const float* beta  = (const float*)d_in[5];
  float* out = (float*)d_out;

  char* ws = (char*)d_ws;
  size_t off = 0;
  auto alloc = [&](size_t bytes) {
    char* p = ws + off;
    off += (bytes + 255) & ~(size_t)255;
    return p;
  };
  unsigned short* xb    = (unsigned short*)alloc((size_t)ROWS * DIN * 2);   // 33.5 MB
  unsigned short* wxb   = (unsigned short*)alloc((size_t)G3 * DIN * 2);
  unsigned short* whfb  = (unsigned short*)alloc((size_t)G3 * HID * 2);
  unsigned short* whbb  = (unsigned short*)alloc((size_t)G3 * HID * 2);
  unsigned short* P     = (unsigned short*)alloc((size_t)ROWS * G3 * 2);    // 100.7 MB
  float* stats          = (float*)alloc(2 * G3 * 4);
  float* params         = (float*)alloc(2 * G3 * 4);
  unsigned short* histf = (unsigned short*)alloc((size_t)T_LEN * BATCH * HID * 2); // 33.5 MB
  unsigned short* histb = (unsigned short*)alloc((size_t)T_LEN * BATCH * HID * 2); // 33.5 MB
  int* cnt              = (int*)alloc(2 * T_LEN * 4);

  hipLaunchKernelGGL(zero_init, dim3(12), dim3(256), 0, stream, stats, cnt);
  hipLaunchKernelGGL(convert_bf16, dim3(16384), dim3(256), 0, stream, x, xb, ROWS * DIN / 4);
  hipLaunchKernelGGL(convert_bf16, dim3(768), dim3(256), 0, stream, Wx, wxb, G3 * DIN / 4);
  hipLaunchKernelGGL(convert_bf16, dim3(768), dim3(256), 0, stream, Whf, whfb, G3 * HID / 4);
  hipLaunchKernelGGL(convert_bf16, dim3(768), dim3(256), 0, stream, Whb, whbb, G3 * HID / 4);
  hipLaunchKernelGGL(gemm_proj, dim3(512, 24), dim3(256), 0, stream, xb, wxb, P);
  hipLaunchKernelGGL(bn_stats, dim3(6, 64), dim3(256), 0, stream, P, stats);
  hipLaunchKernelGGL(bn_final, dim3(6), dim3(256), 0, stream, stats, gamma, beta, params);
  hipLaunchKernelGGL(scan_kernel, dim3(64), dim3(384), 0, stream,
                     P, params, whfb, whbb, histf, histb, cnt);
  hipLaunchKernelGGL(final_add, dim3(16384), dim3(256), 0, stream, histf, histb, out);
}